// Round 1
// baseline (677.386 us; speedup 1.0000x reference)
//
#include <hip/hip_runtime.h>
#include <cstdint>

// Problem constants
#define B_    8192
#define DIN_  1024
#define H_    2048
#define DOUT_ 1024
#define P4_   4
#define E6_   6
#define C_    512
#define C2_   256

typedef __bf16 bf16x8 __attribute__((ext_vector_type(8)));
typedef float  f32x4  __attribute__((ext_vector_type(4)));

__device__ __forceinline__ unsigned short f2bf_bits(float f) {
    unsigned u = __float_as_uint(f);
    unsigned r = (u + 0x7fffu + ((u >> 16) & 1u)) >> 16;   // RNE
    return (unsigned short)r;
}
__device__ __forceinline__ float bf2f(unsigned short s) {
    return __uint_as_float(((unsigned)s) << 16);
}

// async 16B global->LDS (wave-uniform base + lane*16 semantics)
__device__ __forceinline__ void async_load16(void* lds, const void* g) {
    __builtin_amdgcn_global_load_lds(
        (__attribute__((address_space(1))) void*)(uintptr_t)g,
        (__attribute__((address_space(3))) void*)(unsigned int)(uintptr_t)lds,
        16, 0, 0);
}

// ---------------- prepass kernels ----------------

__global__ void convert_f32_bf16_k(const float* __restrict__ in,
                                   unsigned short* __restrict__ out, int n) {
    int i = (blockIdx.x * blockDim.x + threadIdx.x) * 4;
    if (i + 3 < n) {
        float4 v = *(const float4*)(in + i);
        ushort4 o;
        o.x = f2bf_bits(v.x); o.y = f2bf_bits(v.y);
        o.z = f2bf_bits(v.z); o.w = f2bf_bits(v.w);
        *(ushort4*)(out + i) = o;
    }
}

// out[c][r] = bf16(in[r][c]);  in: (R, Cc) f32, out: (Cc, R) bf16. block (32,8)
__global__ void transpose_to_bf16_k(const float* __restrict__ in,
                                    unsigned short* __restrict__ out,
                                    int R, int Cc, long inStrideZ, long outStrideZ) {
    __shared__ float t[32][33];
    in  += (long)blockIdx.z * inStrideZ;
    out += (long)blockIdx.z * outStrideZ;
    int x0 = blockIdx.x << 5, y0 = blockIdx.y << 5;
    int tx = threadIdx.x, ty = threadIdx.y;
#pragma unroll
    for (int j = 0; j < 32; j += 8)
        t[ty + j][tx] = in[(long)(y0 + ty + j) * Cc + x0 + tx];
    __syncthreads();
#pragma unroll
    for (int j = 0; j < 32; j += 8)
        out[(long)(x0 + ty + j) * R + y0 + tx] = f2bf_bits(t[tx][ty + j]);
}

// outT[d][c] = bf16( mean_s W[s][c][d] );  W: (4,512,256), outT: (256,512)
__global__ void wbar_k(const float* __restrict__ W, unsigned short* __restrict__ outT) {
    int id = blockIdx.x * blockDim.x + threadIdx.x;   // 256*512 total
    int d = id >> 9, c = id & 511;
    float s = 0.f;
#pragma unroll
    for (int si = 0; si < 4; si++) s += W[si * (512 * 256) + c * 256 + d];
    outT[id] = f2bf_bits(0.25f * s);
}

// out[d] = mean_s b[s][d]; b: (4,256)
__global__ void bbar_k(const float* __restrict__ b, float* __restrict__ out) {
    int d = threadIdx.x;
    out[d] = 0.25f * (b[d] + b[256 + d] + b[512 + d] + b[768 + d]);
}

// ---------------- elementwise diffusion / sheaf prep ----------------
// per (b,c): reads h[b, p*C+c] p=0..3; writes diffused f32+bf16, base bf16,
// weighted (E,B,C) bf16, d_e=(diff_i - diff_j) (E,B,C) bf16
__global__ void k2_diffuse_k(const unsigned short* __restrict__ hb,
                             const float* __restrict__ incidence,
                             const float* __restrict__ damping,
                             float* __restrict__ outDiff,
                             unsigned short* __restrict__ diffb,
                             unsigned short* __restrict__ baseb,
                             unsigned short* __restrict__ weightedb,
                             unsigned short* __restrict__ debuf) {
    __shared__ float M4[4][4];
    __shared__ float inc2[24];
    int tid = threadIdx.x;
    if (tid < 16) {
        int p = tid >> 2, q = tid & 3;
        float l = 0.f;
#pragma unroll
        for (int e = 0; e < 6; e++) l += incidence[e * 4 + p] * incidence[e * 4 + q];
        M4[p][q] = (p == q ? 1.f : 0.f) - damping[0] * l;
    }
    if (tid < 24) inc2[tid] = incidence[tid];
    __syncthreads();

    int b = blockIdx.x >> 1;
    int c = ((blockIdx.x & 1) << 8) + tid;
    long hoff = (long)b * H_ + c;
    float s0 = bf2f(hb[hoff]);
    float s1 = bf2f(hb[hoff + 512]);
    float s2 = bf2f(hb[hoff + 1024]);
    float s3 = bf2f(hb[hoff + 1536]);

    float d0 = M4[0][0]*s0 + M4[0][1]*s1 + M4[0][2]*s2 + M4[0][3]*s3;
    float d1 = M4[1][0]*s0 + M4[1][1]*s1 + M4[1][2]*s2 + M4[1][3]*s3;
    float d2 = M4[2][0]*s0 + M4[2][1]*s1 + M4[2][2]*s2 + M4[2][3]*s3;
    float d3 = M4[3][0]*s0 + M4[3][1]*s1 + M4[3][2]*s2 + M4[3][3]*s3;

    outDiff[hoff]        = d0;
    outDiff[hoff + 512]  = d1;
    outDiff[hoff + 1024] = d2;
    outDiff[hoff + 1536] = d3;
    diffb[hoff]        = f2bf_bits(d0);
    diffb[hoff + 512]  = f2bf_bits(d1);
    diffb[hoff + 1024] = f2bf_bits(d2);
    diffb[hoff + 1536] = f2bf_bits(d3);
    baseb[(long)b * C_ + c] = f2bf_bits(0.25f * (d0 + d1 + d2 + d3));

#pragma unroll
    for (int e = 0; e < 6; e++) {
        float w = inc2[e*4+0]*s0 + inc2[e*4+1]*s1 + inc2[e*4+2]*s2 + inc2[e*4+3]*s3;
        weightedb[(long)e * (B_ * (long)C_) + (long)b * C_ + c] = f2bf_bits(w);
    }
    float dI[6] = {d0, d0, d0, d1, d1, d2};
    float dJ[6] = {d1, d2, d3, d2, d3, d3};
#pragma unroll
    for (int e = 0; e < 6; e++)
        debuf[(long)e * (B_ * (long)C_) + (long)b * C_ + c] = f2bf_bits(dI[e] - dJ[e]);
}

// ---------------- MFMA GEMM: C = A @ Bt^T (+bias) ----------------
// A: (M,K) bf16 row-major. Bt: (N,K) bf16 row-major. 128x128 tile, BK=64.
// MODE 0: store bf16 to Cb;  1: store f32 to Cf;  2: both;
// MODE 3: atomicAdd per-row sum of squares into red[row]  (batch z)
// MODE 4: atomicAdd global sum of squares into red[0]
template <int MODE>
__global__ __launch_bounds__(256, 2)
void gemm_bt_k(const unsigned short* __restrict__ A, long sAz, int lda,
               const unsigned short* __restrict__ Bt, long sBz, int K,
               const float* __restrict__ bias,
               unsigned short* __restrict__ Cb, int ldcb,
               float* __restrict__ Cf, int ldcf,
               float* __restrict__ red, long sRz) {
    __shared__ __align__(16) unsigned short smA[128 * 64];
    __shared__ __align__(16) unsigned short smB[128 * 64];
    const int tid = threadIdx.x;
    const int lane = tid & 63, w = tid >> 6;
    const int wm = w >> 1, wn = w & 1;
    const int m16 = lane & 15, quad = lane >> 4;
    A  += (long)blockIdx.z * sAz;
    Bt += (long)blockIdx.z * sBz;
    const long rowA0 = (long)blockIdx.y * 128;
    const long rowB0 = (long)blockIdx.x * 128;

    f32x4 acc[4][4];
#pragma unroll
    for (int i = 0; i < 4; i++)
#pragma unroll
        for (int j = 0; j < 4; j++) acc[i][j] = f32x4{0.f, 0.f, 0.f, 0.f};

    for (int k0 = 0; k0 < K; k0 += 64) {
#pragma unroll
        for (int i = 0; i < 4; i++) {
            int chunk = i * 256 + tid;
            int row = chunk >> 3;
            int ke  = (chunk & 7) << 3;
            async_load16(&smA[chunk << 3], A  + (rowA0 + row) * (long)lda + k0 + ke);
            async_load16(&smB[chunk << 3], Bt + (rowB0 + row) * (long)K   + k0 + ke);
        }
        __syncthreads();
#pragma unroll
        for (int kk = 0; kk < 64; kk += 32) {
            bf16x8 af[4], bfv[4];
#pragma unroll
            for (int i = 0; i < 4; i++) {
                af[i]  = *(const bf16x8*)&smA[((wm << 6) + (i << 4) + m16) * 64 + kk + (quad << 3)];
                bfv[i] = *(const bf16x8*)&smB[((wn << 6) + (i << 4) + m16) * 64 + kk + (quad << 3)];
            }
#pragma unroll
            for (int i = 0; i < 4; i++)
#pragma unroll
                for (int j = 0; j < 4; j++)
                    acc[i][j] = __builtin_amdgcn_mfma_f32_16x16x32_bf16(af[i], bfv[j], acc[i][j], 0, 0, 0);
        }
        __syncthreads();
    }

    const long rowBase = rowA0 + (wm << 6);
    const long colBase = rowB0 + (wn << 6);

    if (MODE <= 2) {
#pragma unroll
        for (int j = 0; j < 4; j++) {
            long col = colBase + (j << 4) + m16;
            float bv = bias ? bias[col] : 0.f;
#pragma unroll
            for (int i = 0; i < 4; i++) {
                long row = rowBase + (i << 4) + (quad << 2);
#pragma unroll
                for (int r = 0; r < 4; r++) {
                    float v = acc[i][j][r] + bv;
                    if (MODE == 0 || MODE == 2) Cb[(row + r) * (long)ldcb + col] = f2bf_bits(v);
                    if (MODE == 1 || MODE == 2) Cf[(row + r) * (long)ldcf + col] = v;
                }
            }
        }
    } else if (MODE == 3) {
        float* rz = red + (long)blockIdx.z * sRz;
#pragma unroll
        for (int i = 0; i < 4; i++) {
            float v0 = 0.f, v1 = 0.f, v2 = 0.f, v3 = 0.f;
#pragma unroll
            for (int j = 0; j < 4; j++) {
                float a0 = acc[i][j][0], a1 = acc[i][j][1], a2 = acc[i][j][2], a3 = acc[i][j][3];
                v0 += a0 * a0; v1 += a1 * a1; v2 += a2 * a2; v3 += a3 * a3;
            }
#pragma unroll
            for (int m = 1; m <= 8; m <<= 1) {
                v0 += __shfl_xor(v0, m); v1 += __shfl_xor(v1, m);
                v2 += __shfl_xor(v2, m); v3 += __shfl_xor(v3, m);
            }
            if (m16 == 0) {
                long row = rowBase + (i << 4) + (quad << 2);
                atomicAdd(&rz[row + 0], v0);
                atomicAdd(&rz[row + 1], v1);
                atomicAdd(&rz[row + 2], v2);
                atomicAdd(&rz[row + 3], v3);
            }
        }
    } else {  // MODE 4
        float s = 0.f;
#pragma unroll
        for (int i = 0; i < 4; i++)
#pragma unroll
            for (int j = 0; j < 4; j++)
#pragma unroll
                for (int r = 0; r < 4; r++) { float a = acc[i][j][r]; s += a * a; }
#pragma unroll
        for (int m = 1; m <= 32; m <<= 1) s += __shfl_xor(s, m);
        if (lane == 0) atomicAdd(red, s);
    }
}

// ---------------- finals ----------------
__global__ void f1_h1norm_k(const float* __restrict__ hn, float* __restrict__ out) {
    int b = blockIdx.x * 256 + threadIdx.x;
    float s = 0.f;
#pragma unroll
    for (int e = 0; e < 6; e++) s += sqrtf(hn[e * B_ + b]);
    out[b] = s * (1.f / 6.f);
}

__global__ void f2_h1loss_k(const float* __restrict__ acc, float* __restrict__ out) {
    if (threadIdx.x == 0) out[0] = acc[0] * (1.f / (8192.f * 6.f * 256.f));
}

// ---------------- launcher ----------------
extern "C" void kernel_launch(void* const* d_in, const int* in_sizes, int n_in,
                              void* d_out, int out_size, void* d_ws, size_t ws_size,
                              hipStream_t stream) {
    const float* x     = (const float*)d_in[0];
    const float* fiber = (const float*)d_in[1];
    const float* W_in  = (const float*)d_in[2];
    const float* b_in  = (const float*)d_in[3];
    const float* incid = (const float*)d_in[4];
    const float* sheaf = (const float*)d_in[5];
    const float* damp  = (const float*)d_in[6];
    const float* Wb    = (const float*)d_in[7];
    const float* bb    = (const float*)d_in[8];
    const float* Wf    = (const float*)d_in[9];
    const float* bfv   = (const float*)d_in[10];
    const float* Wt    = (const float*)d_in[11];
    const float* bt    = (const float*)d_in[12];
    const float* Wr    = (const float*)d_in[13];
    const float* Wg    = (const float*)d_in[15];
    const float* bg    = (const float*)d_in[16];
    const float* Wc    = (const float*)d_in[17];
    const float* bc    = (const float*)d_in[18];

    float* out      = (float*)d_out;
    float* outDiff  = out + 8388608;     // B*DOUT
    float* outH1n   = out + 25165824;
    float* outH1l   = out + 25174016;
    float* outTotal = out + 25174017;    // odd offset: scalar f32 stores only

    char* ws = (char*)d_ws;
    size_t o = 0;
    auto alloc = [&](size_t bytes) { size_t r = o; o += (bytes + 255) & ~(size_t)255; return r; };

    // region0: xb (16.78MB) + hb (33.55MB) early; reused as Ab (41.94MB) later
    size_t r0 = alloc(50331648);
    unsigned short* xb = (unsigned short*)(ws + r0);
    unsigned short* hb = (unsigned short*)(ws + r0 + 16777216);
    unsigned short* Ab = (unsigned short*)(ws + r0);
    unsigned short* diffb     = (unsigned short*)(ws + alloc(33554432));
    unsigned short* baseb     = (unsigned short*)(ws + alloc(8388608));
    unsigned short* weightedb = (unsigned short*)(ws + alloc(50331648));
    unsigned short* debuf     = (unsigned short*)(ws + alloc(50331648));
    unsigned short* fiberb    = (unsigned short*)(ws + alloc(8388608));
    unsigned short* cbar      = (unsigned short*)(ws + alloc(8388608));
    unsigned short* WinT   = (unsigned short*)(ws + alloc(4194304));
    unsigned short* WgT    = (unsigned short*)(ws + alloc(8388608));
    unsigned short* WcT    = (unsigned short*)(ws + alloc(5242880));
    unsigned short* WtT    = (unsigned short*)(ws + alloc(524288));
    unsigned short* WrT    = (unsigned short*)(ws + alloc(1572864));
    unsigned short* ShT    = (unsigned short*)(ws + alloc(3145728));
    unsigned short* WbBarT = (unsigned short*)(ws + alloc(262144));
    unsigned short* WfBarT = (unsigned short*)(ws + alloc(262144));
    float* bbarf  = (float*)(ws + alloc(1024));
    float* bfbarf = (float*)(ws + alloc(1024));
    float* hnacc  = (float*)(ws + alloc(6 * 8192 * 4 + 256));
    float* lossacc = hnacc + 6 * 8192;

    (void)hipMemsetAsync(hnacc, 0, 6 * 8192 * 4 + 256, stream);

    // prepass
    convert_f32_bf16_k<<<8192, 256, 0, stream>>>(x, xb, 8388608);
    convert_f32_bf16_k<<<4096, 256, 0, stream>>>(fiber, fiberb, 4194304);
    dim3 tb(32, 8);
    transpose_to_bf16_k<<<dim3(64, 32), tb, 0, stream>>>(W_in, WinT, 1024, 2048, 0, 0);
    transpose_to_bf16_k<<<dim3(64, 64), tb, 0, stream>>>(Wg, WgT, 2048, 2048, 0, 0);
    transpose_to_bf16_k<<<dim3(32, 80), tb, 0, stream>>>(Wc, WcT, 2560, 1024, 0, 0);
    transpose_to_bf16_k<<<dim3(16, 16), tb, 0, stream>>>(Wt, WtT, 512, 512, 0, 0);
    transpose_to_bf16_k<<<dim3(16, 16, 6), tb, 0, stream>>>(sheaf, ShT, 512, 512, 512 * 512, 512 * 512);
    transpose_to_bf16_k<<<dim3(8, 16, 6), tb, 0, stream>>>(Wr, WrT, 512, 256, 512 * 256, 512 * 256);
    wbar_k<<<512, 256, 0, stream>>>(Wb, WbBarT);
    wbar_k<<<512, 256, 0, stream>>>(Wf, WfBarT);
    bbar_k<<<1, 256, 0, stream>>>(bb, bbarf);
    bbar_k<<<1, 256, 0, stream>>>(bfv, bfbarf);

    // G1: h = x @ W_in + b_in   -> hb bf16
    gemm_bt_k<0><<<dim3(16, 64, 1), 256, 0, stream>>>(xb, 0, DIN_, WinT, 0, DIN_,
                                                      b_in, hb, H_, nullptr, 0, nullptr, 0);
    // K2: diffusion / base / weighted / edge-diffs
    k2_diffuse_k<<<16384, 256, 0, stream>>>(hb, incid, damp, outDiff, diffb, baseb, weightedb, debuf);

    // G6: glued = diffused @ Wg + bg  -> Ab[:, 0:2048] bf16
    gemm_bt_k<0><<<dim3(16, 64, 1), 256, 0, stream>>>(diffb, 0, H_, WgT, 0, H_,
                                                      bg, Ab, 2560, nullptr, 0, nullptr, 0);
    // G3: sheaf coboundary row-norms (batched over e)
    gemm_bt_k<3><<<dim3(4, 64, 6), 256, 0, stream>>>(weightedb, (long)B_ * C_, C_, ShT, (long)C_ * C_, C_,
                                                     nullptr, nullptr, 0, nullptr, 0, hnacc, B_);
    // G4: h1 loss sum of squares (batched over e)
    gemm_bt_k<4><<<dim3(2, 64, 6), 256, 0, stream>>>(debuf, (long)B_ * C_, C_, WrT, (long)C2_ * C_, C_,
                                                     nullptr, nullptr, 0, nullptr, 0, lossacc, 0);
    // G5a/b: cbar = [base@WbBar+bbar | fiber@WfBar+bfbar]
    gemm_bt_k<0><<<dim3(2, 64, 1), 256, 0, stream>>>(baseb, 0, C_, WbBarT, 0, C_,
                                                     bbarf, cbar, C_, nullptr, 0, nullptr, 0);
    gemm_bt_k<0><<<dim3(2, 64, 1), 256, 0, stream>>>(fiberb, 0, C_, WfBarT, 0, C_,
                                                     bfbarf, cbar + 256, C_, nullptr, 0, nullptr, 0);
    // G5c: total = cbar @ Wt + bt  -> d_out[total] f32 AND Ab[:, 2048:2560] bf16
    gemm_bt_k<2><<<dim3(4, 64, 1), 256, 0, stream>>>(cbar, 0, C_, WtT, 0, C_,
                                                     bt, Ab + 2048, 2560, outTotal, C_, nullptr, 0);
    // G7: output = Ab @ Wc + bc -> d_out[0] f32
    gemm_bt_k<1><<<dim3(8, 64, 1), 256, 0, stream>>>(Ab, 0, 2560, WcT, 0, 2560,
                                                     bc, nullptr, 0, out, DOUT_, nullptr, 0);
    // finals
    f1_h1norm_k<<<32, 256, 0, stream>>>(hnacc, outH1n);
    f2_h1loss_k<<<1, 64, 0, stream>>>(lossacc, outH1l);

    (void)in_sizes; (void)n_in; (void)out_size; (void)ws_size;
}

// Round 2
// 608.844 us; speedup vs baseline: 1.1126x; 1.1126x over previous
//
#include <hip/hip_runtime.h>
#include <cstdint>

// Problem constants
#define B_    8192
#define DIN_  1024
#define H_    2048
#define DOUT_ 1024
#define P4_   4
#define E6_   6
#define C_    512
#define C2_   256

typedef __bf16 bf16x8 __attribute__((ext_vector_type(8)));
typedef float  f32x4  __attribute__((ext_vector_type(4)));

__device__ __forceinline__ unsigned short f2bf_bits(float f) {
    unsigned u = __float_as_uint(f);
    unsigned r = (u + 0x7fffu + ((u >> 16) & 1u)) >> 16;   // RNE
    return (unsigned short)r;
}
__device__ __forceinline__ float bf2f(unsigned short s) {
    return __uint_as_float(((unsigned)s) << 16);
}

// async 16B global->LDS (wave-uniform base + lane*16 semantics)
__device__ __forceinline__ void async_load16(void* lds, const void* g) {
    __builtin_amdgcn_global_load_lds(
        (__attribute__((address_space(1))) void*)(uintptr_t)g,
        (__attribute__((address_space(3))) void*)(unsigned int)(uintptr_t)lds,
        16, 0, 0);
}

// ---------------- prepass kernels ----------------

__global__ void convert_f32_bf16_k(const float* __restrict__ in,
                                   unsigned short* __restrict__ out, int n) {
    int i = (blockIdx.x * blockDim.x + threadIdx.x) * 4;
    if (i + 3 < n) {
        float4 v = *(const float4*)(in + i);
        ushort4 o;
        o.x = f2bf_bits(v.x); o.y = f2bf_bits(v.y);
        o.z = f2bf_bits(v.z); o.w = f2bf_bits(v.w);
        *(ushort4*)(out + i) = o;
    }
}

// out[c][r] = bf16(in[r][c]);  in: (R, Cc) f32, out: (Cc, R) bf16. block (32,8)
__global__ void transpose_to_bf16_k(const float* __restrict__ in,
                                    unsigned short* __restrict__ out,
                                    int R, int Cc, long inStrideZ, long outStrideZ) {
    __shared__ float t[32][33];
    in  += (long)blockIdx.z * inStrideZ;
    out += (long)blockIdx.z * outStrideZ;
    int x0 = blockIdx.x << 5, y0 = blockIdx.y << 5;
    int tx = threadIdx.x, ty = threadIdx.y;
#pragma unroll
    for (int j = 0; j < 32; j += 8)
        t[ty + j][tx] = in[(long)(y0 + ty + j) * Cc + x0 + tx];
    __syncthreads();
#pragma unroll
    for (int j = 0; j < 32; j += 8)
        out[(long)(x0 + ty + j) * R + y0 + tx] = f2bf_bits(t[tx][ty + j]);
}

// outT[d][c] = bf16( mean_s W[s][c][d] );  W: (4,512,256), outT: (256,512)
__global__ void wbar_k(const float* __restrict__ W, unsigned short* __restrict__ outT) {
    int id = blockIdx.x * blockDim.x + threadIdx.x;   // 256*512 total
    int d = id >> 9, c = id & 511;
    float s = 0.f;
#pragma unroll
    for (int si = 0; si < 4; si++) s += W[si * (512 * 256) + c * 256 + d];
    outT[id] = f2bf_bits(0.25f * s);
}

// out[d] = mean_s b[s][d]; b: (4,256)
__global__ void bbar_k(const float* __restrict__ b, float* __restrict__ out) {
    int d = threadIdx.x;
    out[d] = 0.25f * (b[d] + b[256 + d] + b[512 + d] + b[768 + d]);
}

// ---------------- elementwise diffusion / sheaf prep ----------------
__global__ void k2_diffuse_k(const unsigned short* __restrict__ hb,
                             const float* __restrict__ incidence,
                             const float* __restrict__ damping,
                             float* __restrict__ outDiff,
                             unsigned short* __restrict__ diffb,
                             unsigned short* __restrict__ baseb,
                             unsigned short* __restrict__ weightedb,
                             unsigned short* __restrict__ debuf) {
    __shared__ float M4[4][4];
    __shared__ float inc2[24];
    int tid = threadIdx.x;
    if (tid < 16) {
        int p = tid >> 2, q = tid & 3;
        float l = 0.f;
#pragma unroll
        for (int e = 0; e < 6; e++) l += incidence[e * 4 + p] * incidence[e * 4 + q];
        M4[p][q] = (p == q ? 1.f : 0.f) - damping[0] * l;
    }
    if (tid < 24) inc2[tid] = incidence[tid];
    __syncthreads();

    int b = blockIdx.x >> 1;
    int c = ((blockIdx.x & 1) << 8) + tid;
    long hoff = (long)b * H_ + c;
    float s0 = bf2f(hb[hoff]);
    float s1 = bf2f(hb[hoff + 512]);
    float s2 = bf2f(hb[hoff + 1024]);
    float s3 = bf2f(hb[hoff + 1536]);

    float d0 = M4[0][0]*s0 + M4[0][1]*s1 + M4[0][2]*s2 + M4[0][3]*s3;
    float d1 = M4[1][0]*s0 + M4[1][1]*s1 + M4[1][2]*s2 + M4[1][3]*s3;
    float d2 = M4[2][0]*s0 + M4[2][1]*s1 + M4[2][2]*s2 + M4[2][3]*s3;
    float d3 = M4[3][0]*s0 + M4[3][1]*s1 + M4[3][2]*s2 + M4[3][3]*s3;

    outDiff[hoff]        = d0;
    outDiff[hoff + 512]  = d1;
    outDiff[hoff + 1024] = d2;
    outDiff[hoff + 1536] = d3;
    diffb[hoff]        = f2bf_bits(d0);
    diffb[hoff + 512]  = f2bf_bits(d1);
    diffb[hoff + 1024] = f2bf_bits(d2);
    diffb[hoff + 1536] = f2bf_bits(d3);
    baseb[(long)b * C_ + c] = f2bf_bits(0.25f * (d0 + d1 + d2 + d3));

#pragma unroll
    for (int e = 0; e < 6; e++) {
        float w = inc2[e*4+0]*s0 + inc2[e*4+1]*s1 + inc2[e*4+2]*s2 + inc2[e*4+3]*s3;
        weightedb[(long)e * (B_ * (long)C_) + (long)b * C_ + c] = f2bf_bits(w);
    }
    float dI[6] = {d0, d0, d0, d1, d1, d2};
    float dJ[6] = {d1, d2, d3, d2, d3, d3};
#pragma unroll
    for (int e = 0; e < 6; e++)
        debuf[(long)e * (B_ * (long)C_) + (long)b * C_ + c] = f2bf_bits(dI[e] - dJ[e]);
}

// ---------------- MFMA GEMM: C = A @ Bt^T (+bias) ----------------
// A: (M,K) bf16 row-major. Bt: (N,K) bf16 row-major. 128x128 tile, BK=64.
// LDS layout XOR-swizzled at 16B-chunk granularity: physical chunk
// pc = logical_chunk ^ (row & 7). Staging permutes the GLOBAL source column
// (LDS dest of global_load_lds is fixed wave-uniform+lane*16); fragment reads
// apply the same XOR -> each 8-lane LDS phase covers all 32 banks (no conflict).
// MODE 0: store bf16 to Cb;  1: store f32 to Cf;  2: both;
// MODE 3: atomicAdd per-row sum of squares into red[row]  (batch z)
// MODE 4: atomicAdd global sum of squares into red[0]
template <int MODE>
__global__ __launch_bounds__(256, 2)
void gemm_bt_k(const unsigned short* __restrict__ A, long sAz, int lda,
               const unsigned short* __restrict__ Bt, long sBz, int K,
               const float* __restrict__ bias,
               unsigned short* __restrict__ Cb, int ldcb,
               float* __restrict__ Cf, int ldcf,
               float* __restrict__ red, long sRz) {
    __shared__ __align__(16) unsigned short smA[128 * 64];
    __shared__ __align__(16) unsigned short smB[128 * 64];
    const int tid = threadIdx.x;
    const int lane = tid & 63, w = tid >> 6;
    const int wm = w >> 1, wn = w & 1;
    const int m16 = lane & 15, quad = lane >> 4;
    const int m7 = m16 & 7;
    A  += (long)blockIdx.z * sAz;
    Bt += (long)blockIdx.z * sBz;
    const long rowA0 = (long)blockIdx.y * 128;
    const long rowB0 = (long)blockIdx.x * 128;

    f32x4 acc[4][4];
#pragma unroll
    for (int i = 0; i < 4; i++)
#pragma unroll
        for (int j = 0; j < 4; j++) acc[i][j] = f32x4{0.f, 0.f, 0.f, 0.f};

    for (int k0 = 0; k0 < K; k0 += 64) {
#pragma unroll
        for (int i = 0; i < 4; i++) {
            int chunk = i * 256 + tid;
            int row = chunk >> 3;
            int keS = ((chunk & 7) ^ (row & 7)) << 3;   // swizzled global column
            async_load16(&smA[chunk << 3], A  + (rowA0 + row) * (long)lda + k0 + keS);
            async_load16(&smB[chunk << 3], Bt + (rowB0 + row) * (long)K   + k0 + keS);
        }
        __syncthreads();
#pragma unroll
        for (int kk = 0; kk < 64; kk += 32) {
            const int pc = (((kk >> 3) + quad) ^ m7) << 3;  // swizzled chunk offset (elems)
            bf16x8 af[4], bfv[4];
#pragma unroll
            for (int i = 0; i < 4; i++) {
                af[i]  = *(const bf16x8*)&smA[((wm << 6) + (i << 4) + m16) * 64 + pc];
                bfv[i] = *(const bf16x8*)&smB[((wn << 6) + (i << 4) + m16) * 64 + pc];
            }
#pragma unroll
            for (int i = 0; i < 4; i++)
#pragma unroll
                for (int j = 0; j < 4; j++)
                    acc[i][j] = __builtin_amdgcn_mfma_f32_16x16x32_bf16(af[i], bfv[j], acc[i][j], 0, 0, 0);
        }
        __syncthreads();
    }

    const long rowBase = rowA0 + (wm << 6);
    const long colBase = rowB0 + (wn << 6);

    if (MODE <= 2) {
#pragma unroll
        for (int j = 0; j < 4; j++) {
            long col = colBase + (j << 4) + m16;
            float bv = bias ? bias[col] : 0.f;
#pragma unroll
            for (int i = 0; i < 4; i++) {
                long row = rowBase + (i << 4) + (quad << 2);
#pragma unroll
                for (int r = 0; r < 4; r++) {
                    float v = acc[i][j][r] + bv;
                    if (MODE == 0 || MODE == 2) Cb[(row + r) * (long)ldcb + col] = f2bf_bits(v);
                    if (MODE == 1 || MODE == 2) Cf[(row + r) * (long)ldcf + col] = v;
                }
            }
        }
    } else if (MODE == 3) {
        float* rz = red + (long)blockIdx.z * sRz;
#pragma unroll
        for (int i = 0; i < 4; i++) {
            float v0 = 0.f, v1 = 0.f, v2 = 0.f, v3 = 0.f;
#pragma unroll
            for (int j = 0; j < 4; j++) {
                float a0 = acc[i][j][0], a1 = acc[i][j][1], a2 = acc[i][j][2], a3 = acc[i][j][3];
                v0 += a0 * a0; v1 += a1 * a1; v2 += a2 * a2; v3 += a3 * a3;
            }
#pragma unroll
            for (int m = 1; m <= 8; m <<= 1) {
                v0 += __shfl_xor(v0, m); v1 += __shfl_xor(v1, m);
                v2 += __shfl_xor(v2, m); v3 += __shfl_xor(v3, m);
            }
            if (m16 == 0) {
                long row = rowBase + (i << 4) + (quad << 2);
                atomicAdd(&rz[row + 0], v0);
                atomicAdd(&rz[row + 1], v1);
                atomicAdd(&rz[row + 2], v2);
                atomicAdd(&rz[row + 3], v3);
            }
        }
    } else {  // MODE 4
        float s = 0.f;
#pragma unroll
        for (int i = 0; i < 4; i++)
#pragma unroll
            for (int j = 0; j < 4; j++)
#pragma unroll
                for (int r = 0; r < 4; r++) { float a = acc[i][j][r]; s += a * a; }
#pragma unroll
        for (int m = 1; m <= 32; m <<= 1) s += __shfl_xor(s, m);
        if (lane == 0) atomicAdd(red, s);
    }
}

// ---------------- finals ----------------
__global__ void f1_h1norm_k(const float* __restrict__ hn, float* __restrict__ out) {
    int b = blockIdx.x * 256 + threadIdx.x;
    float s = 0.f;
#pragma unroll
    for (int e = 0; e < 6; e++) s += sqrtf(hn[e * B_ + b]);
    out[b] = s * (1.f / 6.f);
}

__global__ void f2_h1loss_k(const float* __restrict__ acc, float* __restrict__ out) {
    if (threadIdx.x == 0) out[0] = acc[0] * (1.f / (8192.f * 6.f * 256.f));
}

// ---------------- launcher ----------------
extern "C" void kernel_launch(void* const* d_in, const int* in_sizes, int n_in,
                              void* d_out, int out_size, void* d_ws, size_t ws_size,
                              hipStream_t stream) {
    const float* x     = (const float*)d_in[0];
    const float* fiber = (const float*)d_in[1];
    const float* W_in  = (const float*)d_in[2];
    const float* b_in  = (const float*)d_in[3];
    const float* incid = (const float*)d_in[4];
    const float* sheaf = (const float*)d_in[5];
    const float* damp  = (const float*)d_in[6];
    const float* Wb    = (const float*)d_in[7];
    const float* bb    = (const float*)d_in[8];
    const float* Wf    = (const float*)d_in[9];
    const float* bfv   = (const float*)d_in[10];
    const float* Wt    = (const float*)d_in[11];
    const float* bt    = (const float*)d_in[12];
    const float* Wr    = (const float*)d_in[13];
    const float* Wg    = (const float*)d_in[15];
    const float* bg    = (const float*)d_in[16];
    const float* Wc    = (const float*)d_in[17];
    const float* bc    = (const float*)d_in[18];

    float* out      = (float*)d_out;
    float* outDiff  = out + 8388608;     // B*DOUT
    float* outH1n   = out + 25165824;
    float* outH1l   = out + 25174016;
    float* outTotal = out + 25174017;

    char* ws = (char*)d_ws;
    size_t o = 0;
    auto alloc = [&](size_t bytes) { size_t r = o; o += (bytes + 255) & ~(size_t)255; return r; };

    size_t r0 = alloc(50331648);
    unsigned short* xb = (unsigned short*)(ws + r0);
    unsigned short* hb = (unsigned short*)(ws + r0 + 16777216);
    unsigned short* Ab = (unsigned short*)(ws + r0);
    unsigned short* diffb     = (unsigned short*)(ws + alloc(33554432));
    unsigned short* baseb     = (unsigned short*)(ws + alloc(8388608));
    unsigned short* weightedb = (unsigned short*)(ws + alloc(50331648));
    unsigned short* debuf     = (unsigned short*)(ws + alloc(50331648));
    unsigned short* fiberb    = (unsigned short*)(ws + alloc(8388608));
    unsigned short* cbar      = (unsigned short*)(ws + alloc(8388608));
    unsigned short* WinT   = (unsigned short*)(ws + alloc(4194304));
    unsigned short* WgT    = (unsigned short*)(ws + alloc(8388608));
    unsigned short* WcT    = (unsigned short*)(ws + alloc(5242880));
    unsigned short* WtT    = (unsigned short*)(ws + alloc(524288));
    unsigned short* WrT    = (unsigned short*)(ws + alloc(1572864));
    unsigned short* ShT    = (unsigned short*)(ws + alloc(3145728));
    unsigned short* WbBarT = (unsigned short*)(ws + alloc(262144));
    unsigned short* WfBarT = (unsigned short*)(ws + alloc(262144));
    float* bbarf  = (float*)(ws + alloc(1024));
    float* bfbarf = (float*)(ws + alloc(1024));
    float* hnacc  = (float*)(ws + alloc(6 * 8192 * 4 + 256));
    float* lossacc = hnacc + 6 * 8192;

    (void)hipMemsetAsync(hnacc, 0, 6 * 8192 * 4 + 256, stream);

    // prepass
    convert_f32_bf16_k<<<8192, 256, 0, stream>>>(x, xb, 8388608);
    convert_f32_bf16_k<<<4096, 256, 0, stream>>>(fiber, fiberb, 4194304);
    dim3 tb(32, 8);
    transpose_to_bf16_k<<<dim3(64, 32), tb, 0, stream>>>(W_in, WinT, 1024, 2048, 0, 0);
    transpose_to_bf16_k<<<dim3(64, 64), tb, 0, stream>>>(Wg, WgT, 2048, 2048, 0, 0);
    transpose_to_bf16_k<<<dim3(32, 80), tb, 0, stream>>>(Wc, WcT, 2560, 1024, 0, 0);
    transpose_to_bf16_k<<<dim3(16, 16), tb, 0, stream>>>(Wt, WtT, 512, 512, 0, 0);
    transpose_to_bf16_k<<<dim3(16, 16, 6), tb, 0, stream>>>(sheaf, ShT, 512, 512, 512 * 512, 512 * 512);
    transpose_to_bf16_k<<<dim3(8, 16, 6), tb, 0, stream>>>(Wr, WrT, 512, 256, 512 * 256, 512 * 256);
    wbar_k<<<512, 256, 0, stream>>>(Wb, WbBarT);
    wbar_k<<<512, 256, 0, stream>>>(Wf, WfBarT);
    bbar_k<<<1, 256, 0, stream>>>(bb, bbarf);
    bbar_k<<<1, 256, 0, stream>>>(bfv, bfbarf);

    // G1: h = x @ W_in + b_in   -> hb bf16
    gemm_bt_k<0><<<dim3(16, 64, 1), 256, 0, stream>>>(xb, 0, DIN_, WinT, 0, DIN_,
                                                      b_in, hb, H_, nullptr, 0, nullptr, 0);
    // K2: diffusion / base / weighted / edge-diffs
    k2_diffuse_k<<<16384, 256, 0, stream>>>(hb, incid, damp, outDiff, diffb, baseb, weightedb, debuf);

    // G6: glued = diffused @ Wg + bg  -> Ab[:, 0:2048] bf16
    gemm_bt_k<0><<<dim3(16, 64, 1), 256, 0, stream>>>(diffb, 0, H_, WgT, 0, H_,
                                                      bg, Ab, 2560, nullptr, 0, nullptr, 0);
    // G3: sheaf coboundary row-norms (batched over e)
    gemm_bt_k<3><<<dim3(4, 64, 6), 256, 0, stream>>>(weightedb, (long)B_ * C_, C_, ShT, (long)C_ * C_, C_,
                                                     nullptr, nullptr, 0, nullptr, 0, hnacc, B_);
    // G4: h1 loss sum of squares (batched over e)
    gemm_bt_k<4><<<dim3(2, 64, 6), 256, 0, stream>>>(debuf, (long)B_ * C_, C_, WrT, (long)C2_ * C_, C_,
                                                     nullptr, nullptr, 0, nullptr, 0, lossacc, 0);
    // G5a/b: cbar = [base@WbBar+bbar | fiber@WfBar+bfbar]
    gemm_bt_k<0><<<dim3(2, 64, 1), 256, 0, stream>>>(baseb, 0, C_, WbBarT, 0, C_,
                                                     bbarf, cbar, C_, nullptr, 0, nullptr, 0);
    gemm_bt_k<0><<<dim3(2, 64, 1), 256, 0, stream>>>(fiberb, 0, C_, WfBarT, 0, C_,
                                                     bfbarf, cbar + 256, C_, nullptr, 0, nullptr, 0);
    // G5c: total = cbar @ Wt + bt  -> d_out[total] f32 AND Ab[:, 2048:2560] bf16
    gemm_bt_k<2><<<dim3(4, 64, 1), 256, 0, stream>>>(cbar, 0, C_, WtT, 0, C_,
                                                     bt, Ab + 2048, 2560, outTotal, C_, nullptr, 0);
    // G7: output = Ab @ Wc + bc -> d_out[0] f32
    gemm_bt_k<1><<<dim3(8, 64, 1), 256, 0, stream>>>(Ab, 0, 2560, WcT, 0, 2560,
                                                     bc, nullptr, 0, out, DOUT_, nullptr, 0);
    // finals
    f1_h1norm_k<<<32, 256, 0, stream>>>(hnacc, outH1n);
    f2_h1loss_k<<<1, 64, 0, stream>>>(lossacc, outH1l);

    (void)in_sizes; (void)n_in; (void)out_size; (void)ws_size;
}